// Round 1
// baseline (235.664 us; speedup 1.0000x reference)
//
#include <hip/hip_runtime.h>
#include <hip/hip_bf16.h>
#include <math.h>

#define S_ 64
#define B_ 128
#define H_ 768
#define A_ 768

typedef __bf16 bf16_t;
typedef __attribute__((ext_vector_type(8))) __bf16 bf16x8;
typedef __attribute__((ext_vector_type(4))) __bf16 bf16x4;
typedef __attribute__((ext_vector_type(4))) float f32x4;

#define LDSPAD 40   // 40 bf16 = 80 B row: 16B-aligned for ds_read_b128, 2-way bank alias (free)

// Batched GEMM: for s in [0,64): C_s = [topic; image_s; text_s] @ Wv[s] + bv[s]  (384x768)
// plus group 64: Q = topic @ Wq + bq (128x768, f32 out).
// Tiles: 128x128 per block, 4 waves of 64x64, BK=32, mfma_f32_16x16x32_bf16.
__global__ __launch_bounds__(256, 2)
void mm_gemm_kernel(const float* __restrict__ topic,
                    const float* __restrict__ image,
                    const float* __restrict__ text,
                    const float* __restrict__ Wq,
                    const float* __restrict__ bq,
                    const float* __restrict__ Wv,
                    const float* __restrict__ bv,
                    bf16_t* __restrict__ Vws,
                    float*  __restrict__ Qws)
{
    __shared__ bf16_t Alds[128][LDSPAD];   // [m][k] bf16
    __shared__ bf16_t Blds[128][LDSPAD];   // [n][k] bf16 (Wv transposed)

    const int bid = blockIdx.x;
    const int tid = threadIdx.x;
    const bool isQ = (bid >= S_ * 18);
    int s, tm, tn;
    if (isQ) { s = 0; tm = 0; tn = bid - S_ * 18; }
    else     { s = bid / 18; const int t = bid % 18; tm = t / 6; tn = t % 6; }

    // ---- A staging: thread owns row ar, 16 consecutive k (row-major float4 loads) ----
    const int ar  = tid >> 1;            // 0..127
    const int aks = (tid & 1) * 16;      // k base 0 or 16
    const float* arow;
    if (isQ) {
        arow = topic + (size_t)ar * H_;
    } else {
        const int am  = tm * 128 + ar;
        const int sel = am >> 7;         // 0 topic, 1 image, 2 text (tm == sel)
        const int b   = am & 127;
        if (sel == 0)      arow = topic + (size_t)b * H_;
        else if (sel == 1) arow = image + ((size_t)s * B_ + b) * H_;
        else               arow = text  + ((size_t)s * B_ + b) * H_;
    }
    const int arot = (ar >> 3) & 3;      // write-order rotation (bank spread)

    // ---- B staging: thread owns column bn, 16 k's (strided scalar loads, coalesced over lanes) ----
    const int bn  = tid & 127;           // 0..127
    const int bks = (tid >> 7) * 16;     // k base 0 or 16
    const float* wbase = isQ ? Wq : (Wv + (size_t)s * H_ * A_);
    const float* bcolp = wbase + (size_t)(tn * 128 + bn);
    const int brot = (bn >> 3) & 3;

    // ---- wave / fragment config ----
    const int wave = tid >> 6;
    const int lane = tid & 63;
    const int wr = wave >> 1;            // wave row 0..1 (64 rows each)
    const int wc = wave & 1;             // wave col 0..1
    const int fr = lane & 15;            // row(A)/col(B) within 16
    const int fg = lane >> 4;            // k-group: k = fg*8 + j

    f32x4 acc[4][4];
    #pragma unroll
    for (int i = 0; i < 4; ++i)
        #pragma unroll
        for (int j = 0; j < 4; ++j)
            acc[i][j] = (f32x4){0.f, 0.f, 0.f, 0.f};

    for (int k0 = 0; k0 < H_; k0 += 32) {
        // global loads (issued before barrier to overlap)
        float4 av[4];
        const float4* ap = reinterpret_cast<const float4*>(arow + k0 + aks);
        #pragma unroll
        for (int i = 0; i < 4; ++i) av[i] = ap[i];
        float bvr[16];
        #pragma unroll
        for (int j = 0; j < 16; ++j) bvr[j] = bcolp[(size_t)(k0 + bks + j) * A_];

        __syncthreads();   // previous iter's fragment reads complete

        #pragma unroll
        for (int i = 0; i < 4; ++i) {            // A: [m][k]
            const int j = (i + arot) & 3;
            bf16x4 c;
            c[0] = (bf16_t)av[j].x; c[1] = (bf16_t)av[j].y;
            c[2] = (bf16_t)av[j].z; c[3] = (bf16_t)av[j].w;
            *reinterpret_cast<bf16x4*>(&Alds[ar][aks + 4*j]) = c;
        }
        #pragma unroll
        for (int i = 0; i < 4; ++i) {            // B transposed: [n][k]
            const int j = (i + brot) & 3;
            bf16x4 c;
            c[0] = (bf16_t)bvr[4*j+0]; c[1] = (bf16_t)bvr[4*j+1];
            c[2] = (bf16_t)bvr[4*j+2]; c[3] = (bf16_t)bvr[4*j+3];
            *reinterpret_cast<bf16x4*>(&Blds[bn][bks + 4*j]) = c;
        }
        __syncthreads();   // tiles visible

        bf16x8 afrag[4], bfrag[4];
        #pragma unroll
        for (int mi = 0; mi < 4; ++mi)
            afrag[mi] = *reinterpret_cast<const bf16x8*>(&Alds[wr*64 + mi*16 + fr][fg*8]);
        #pragma unroll
        for (int ni = 0; ni < 4; ++ni)
            bfrag[ni] = *reinterpret_cast<const bf16x8*>(&Blds[wc*64 + ni*16 + fr][fg*8]);
        #pragma unroll
        for (int mi = 0; mi < 4; ++mi)
            #pragma unroll
            for (int ni = 0; ni < 4; ++ni)
                acc[mi][ni] = __builtin_amdgcn_mfma_f32_16x16x32_bf16(
                    afrag[mi], bfrag[ni], acc[mi][ni], 0, 0, 0);
    }

    // ---- epilogue: C/D mapping col = lane&15, row = (lane>>4)*4 + j ----
    if (isQ) {
        #pragma unroll
        for (int ni = 0; ni < 4; ++ni) {
            const int n = tn*128 + wc*64 + ni*16 + fr;
            const float bias = bq[n];
            #pragma unroll
            for (int mi = 0; mi < 4; ++mi)
                #pragma unroll
                for (int j = 0; j < 4; ++j) {
                    const int m = wr*64 + mi*16 + fg*4 + j;   // b index (0..127)
                    Qws[(size_t)m * A_ + n] = acc[mi][ni][j] + bias;
                }
        }
    } else {
        const float* bvrow = bv + (size_t)s * A_;
        #pragma unroll
        for (int ni = 0; ni < 4; ++ni) {
            const int n = tn*128 + wc*64 + ni*16 + fr;
            const float bias = bvrow[n];
            #pragma unroll
            for (int mi = 0; mi < 4; ++mi)
                #pragma unroll
                for (int j = 0; j < 4; ++j) {
                    const int b = wr*64 + mi*16 + fg*4 + j;   // row within tile = b (kk = tm)
                    Vws[(((size_t)s * B_ + b) * 3 + tm) * A_ + n] = (bf16_t)(acc[mi][ni][j] + bias);
                }
        }
    }
}

// One wave per (s,b): scores = Q.V/sqrt(A), softmax over 3, out = sum attn_k * V_k
__global__ __launch_bounds__(256)
void mm_attn_kernel(const bf16_t* __restrict__ Vws,
                    const float* __restrict__ Qws,
                    float* __restrict__ out)
{
    const int wave = threadIdx.x >> 6;
    const int lane = threadIdx.x & 63;
    const int p = blockIdx.x * 4 + wave;     // 0..8191
    const int s = p >> 7;
    const int b = p & 127;
    const float*  qrow  = Qws + (size_t)b * A_;
    const bf16_t* vbase = Vws + ((size_t)s * B_ + b) * 3 * A_;

    float4 qv[3];
    bf16x4 vv[3][3];
    float p0 = 0.f, p1 = 0.f, p2 = 0.f;
    #pragma unroll
    for (int j = 0; j < 3; ++j) {
        const int a = lane * 4 + j * 256;
        qv[j]    = *reinterpret_cast<const float4*>(qrow + a);
        vv[0][j] = *reinterpret_cast<const bf16x4*>(vbase + 0*A_ + a);
        vv[1][j] = *reinterpret_cast<const bf16x4*>(vbase + 1*A_ + a);
        vv[2][j] = *reinterpret_cast<const bf16x4*>(vbase + 2*A_ + a);
        p0 += qv[j].x*(float)vv[0][j][0] + qv[j].y*(float)vv[0][j][1]
            + qv[j].z*(float)vv[0][j][2] + qv[j].w*(float)vv[0][j][3];
        p1 += qv[j].x*(float)vv[1][j][0] + qv[j].y*(float)vv[1][j][1]
            + qv[j].z*(float)vv[1][j][2] + qv[j].w*(float)vv[1][j][3];
        p2 += qv[j].x*(float)vv[2][j][0] + qv[j].y*(float)vv[2][j][1]
            + qv[j].z*(float)vv[2][j][2] + qv[j].w*(float)vv[2][j][3];
    }
    #pragma unroll
    for (int d = 1; d < 64; d <<= 1) {
        p0 += __shfl_xor(p0, d);
        p1 += __shfl_xor(p1, d);
        p2 += __shfl_xor(p2, d);
    }
    const float norm = 0.03608439182435161f;   // 1/sqrt(768)
    const float s0 = p0 * norm, s1 = p1 * norm, s2 = p2 * norm;
    const float mx = fmaxf(s0, fmaxf(s1, s2));
    const float e0 = expf(s0 - mx), e1 = expf(s1 - mx), e2 = expf(s2 - mx);
    const float inv = 1.f / (e0 + e1 + e2);
    const float a0 = e0 * inv, a1 = e1 * inv, a2 = e2 * inv;

    float* orow = out + ((size_t)s * B_ + b) * A_;
    #pragma unroll
    for (int j = 0; j < 3; ++j) {
        const int a = lane * 4 + j * 256;
        float4 o;
        o.x = a0*(float)vv[0][j][0] + a1*(float)vv[1][j][0] + a2*(float)vv[2][j][0];
        o.y = a0*(float)vv[0][j][1] + a1*(float)vv[1][j][1] + a2*(float)vv[2][j][1];
        o.z = a0*(float)vv[0][j][2] + a1*(float)vv[1][j][2] + a2*(float)vv[2][j][2];
        o.w = a0*(float)vv[0][j][3] + a1*(float)vv[1][j][3] + a2*(float)vv[2][j][3];
        *reinterpret_cast<float4*>(orow + a) = o;
    }
}

extern "C" void kernel_launch(void* const* d_in, const int* in_sizes, int n_in,
                              void* d_out, int out_size, void* d_ws, size_t ws_size,
                              hipStream_t stream)
{
    const float* topic = (const float*)d_in[0];
    const float* image = (const float*)d_in[1];
    const float* text  = (const float*)d_in[2];
    const float* Wq    = (const float*)d_in[3];
    const float* bq    = (const float*)d_in[4];
    const float* Wv    = (const float*)d_in[5];
    const float* bv    = (const float*)d_in[6];
    float* out = (float*)d_out;

    // workspace layout: V bf16 [S][B][3][A] (37.75 MB), then Q f32 [B][A] (384 KB)
    bf16_t* Vws = (bf16_t*)d_ws;
    float*  Qws = (float*)((char*)d_ws + (size_t)S_ * B_ * 3 * A_ * sizeof(bf16_t));

    mm_gemm_kernel<<<S_ * 18 + 6, 256, 0, stream>>>(topic, image, text, Wq, bq, Wv, bv, Vws, Qws);
    mm_attn_kernel<<<S_ * B_ / 4, 256, 0, stream>>>(Vws, Qws, out);
}

// Round 2
// 147.764 us; speedup vs baseline: 1.5949x; 1.5949x over previous
//
#include <hip/hip_runtime.h>
#include <hip/hip_bf16.h>
#include <math.h>

#define S_ 64
#define B_ 128
#define H_ 768
#define A_ 768

typedef __bf16 bf16_t;
typedef __attribute__((ext_vector_type(8))) __bf16 bf16x8;
typedef __attribute__((ext_vector_type(4))) __bf16 bf16x4;
typedef __attribute__((ext_vector_type(4))) float f32x4;

// ============================================================================
// FAST PATH
// ============================================================================

// ---- prep 1: f32 -> bf16 elementwise convert, 8 elems/thread ----
__global__ __launch_bounds__(256)
void convert_kernel(const float* __restrict__ in, bf16_t* __restrict__ out, int n8) {
    int i = blockIdx.x * blockDim.x + threadIdx.x;
    if (i >= n8) return;
    const float4* p = reinterpret_cast<const float4*>(in) + (size_t)i * 2;
    float4 a = p[0], b = p[1];
    bf16x8 o;
    o[0]=(bf16_t)a.x; o[1]=(bf16_t)a.y; o[2]=(bf16_t)a.z; o[3]=(bf16_t)a.w;
    o[4]=(bf16_t)b.x; o[5]=(bf16_t)b.y; o[6]=(bf16_t)b.z; o[7]=(bf16_t)b.w;
    reinterpret_cast<bf16x8*>(out)[i] = o;
}

// ---- prep 2: Wv [s][h][a] f32 -> WT [s][a][h] bf16  (s==64 slab = Wq) ----
// 32x32 tiles via LDS; pad 37 (2-way max bank alias on read phase).
__global__ __launch_bounds__(256)
void transpose_kernel(const float* __restrict__ Wv, const float* __restrict__ Wq,
                      bf16_t* __restrict__ WT) {
    __shared__ float Tl[32][37];
    const int bid = blockIdx.x;
    const int s  = bid / 576;
    const int t  = bid % 576;
    const int th = t / 24, ta = t % 24;
    const float* src = (s < S_) ? (Wv + (size_t)s * H_ * A_) : Wq;
    const int tid = threadIdx.x;
    const int r = tid >> 3, c = (tid & 7) * 4;
    float4 v = *reinterpret_cast<const float4*>(src + (size_t)(th*32 + r) * A_ + ta*32 + c);
    Tl[r][c+0] = v.x; Tl[r][c+1] = v.y; Tl[r][c+2] = v.z; Tl[r][c+3] = v.w;
    __syncthreads();
    const int al = tid >> 3, hb = (tid & 7) * 4;
    bf16x4 o;
    o[0]=(bf16_t)Tl[hb+0][al]; o[1]=(bf16_t)Tl[hb+1][al];
    o[2]=(bf16_t)Tl[hb+2][al]; o[3]=(bf16_t)Tl[hb+3][al];
    bf16_t* dst = WT + (size_t)s * A_ * H_ + (size_t)(ta*32 + al) * H_ + th*32 + hb;
    *reinterpret_cast<bf16x4*>(dst) = o;
}

// ---- async global->LDS helper (16 B per lane; LDS dest = wave-uniform base) ----
__device__ __forceinline__ void glds16(const bf16_t* g, bf16_t* l) {
    __builtin_amdgcn_global_load_lds(
        (const __attribute__((address_space(1))) uint32_t*)(g),
        (__attribute__((address_space(3))) uint32_t*)(l), 16, 0, 0);
}

// ---- main GEMM: all-bf16, m97 structure. 128x128 tile, BK=32, 4 waves ----
// blocks: 64 s * (3 m-tiles * 6 n-tiles) + 6 Q-tiles
__global__ __launch_bounds__(256)
void gemm_kernel(const bf16_t* __restrict__ topicB,
                 const bf16_t* __restrict__ imageB,
                 const bf16_t* __restrict__ textB,
                 const bf16_t* __restrict__ WT,
                 const float* __restrict__ bq,
                 const float* __restrict__ bv,
                 bf16_t* __restrict__ Vws, float* __restrict__ Qws)
{
    __shared__ bf16_t Al[128 * 32];   // [row][k] linear, row stride 32 bf16 = 64 B
    __shared__ bf16_t Bl[128 * 32];

    const int bid = blockIdx.x, tid = threadIdx.x;
    const bool isQ = (bid >= S_ * 18);
    int s, tm, tn;
    if (isQ) { s = S_; tm = 0; tn = bid - S_ * 18; }
    else     { s = bid / 18; const int t = bid % 18; tm = t / 6; tn = t % 6; }

    const bf16_t* Abase;
    if (isQ || tm == 0) Abase = topicB;
    else if (tm == 1)   Abase = imageB + (size_t)s * B_ * H_;
    else                Abase = textB  + (size_t)s * B_ * H_;
    const bf16_t* Bbase = WT + (size_t)s * A_ * H_ + (size_t)(tn * 128) * H_;

    // glds chunk mapping: chunk i (16 B) -> row i>>2, k-chunk (i&3)*8
    const int wv = tid >> 6, lane = tid & 63;
    const int i0 = wv * 128 + lane;
    const int i1 = i0 + 64;
    const bf16_t* gA0 = Abase + (size_t)(i0 >> 2) * H_ + (i0 & 3) * 8;
    const bf16_t* gA1 = Abase + (size_t)(i1 >> 2) * H_ + (i1 & 3) * 8;
    const bf16_t* gB0 = Bbase + (size_t)(i0 >> 2) * H_ + (i0 & 3) * 8;
    const bf16_t* gB1 = Bbase + (size_t)(i1 >> 2) * H_ + (i1 & 3) * 8;
    bf16_t* lA0 = Al + (wv * 2 + 0) * 512;   // wave-uniform LDS bases (1 KB regions)
    bf16_t* lA1 = Al + (wv * 2 + 1) * 512;
    bf16_t* lB0 = Bl + (wv * 2 + 0) * 512;
    bf16_t* lB1 = Bl + (wv * 2 + 1) * 512;

    const int wr = wv >> 1, wc = wv & 1;
    const int fr = lane & 15, fg = lane >> 4;

    f32x4 acc[4][4];
    #pragma unroll
    for (int i = 0; i < 4; ++i)
        #pragma unroll
        for (int j = 0; j < 4; ++j)
            acc[i][j] = (f32x4){0.f, 0.f, 0.f, 0.f};

    for (int k0 = 0; k0 < H_; k0 += 32) {
        __syncthreads();                       // prev iter's frag reads done
        glds16(gA0 + k0, lA0);
        glds16(gA1 + k0, lA1);
        glds16(gB0 + k0, lB0);
        glds16(gB1 + k0, lB1);
        __syncthreads();                       // vmcnt(0) drain: tiles visible

        bf16x8 af[4], bfr[4];
        #pragma unroll
        for (int mi = 0; mi < 4; ++mi)
            af[mi] = *reinterpret_cast<const bf16x8*>(Al + (wr*64 + mi*16 + fr) * 32 + fg*8);
        #pragma unroll
        for (int ni = 0; ni < 4; ++ni)
            bfr[ni] = *reinterpret_cast<const bf16x8*>(Bl + (wc*64 + ni*16 + fr) * 32 + fg*8);
        #pragma unroll
        for (int mi = 0; mi < 4; ++mi)
            #pragma unroll
            for (int ni = 0; ni < 4; ++ni)
                acc[mi][ni] = __builtin_amdgcn_mfma_f32_16x16x32_bf16(
                    af[mi], bfr[ni], acc[mi][ni], 0, 0, 0);
    }

    // epilogue: C/D map col = lane&15, row = (lane>>4)*4 + j
    if (isQ) {
        #pragma unroll
        for (int ni = 0; ni < 4; ++ni) {
            const int n = tn*128 + wc*64 + ni*16 + fr;
            const float bias = bq[n];
            #pragma unroll
            for (int mi = 0; mi < 4; ++mi)
                #pragma unroll
                for (int j = 0; j < 4; ++j) {
                    const int m = wr*64 + mi*16 + fg*4 + j;   // b index
                    Qws[(size_t)m * A_ + n] = acc[mi][ni][j] + bias;
                }
        }
    } else {
        const float* bvrow = bv + (size_t)s * A_;
        #pragma unroll
        for (int ni = 0; ni < 4; ++ni) {
            const int n = tn*128 + wc*64 + ni*16 + fr;
            const float bias = bvrow[n];
            #pragma unroll
            for (int mi = 0; mi < 4; ++mi)
                #pragma unroll
                for (int j = 0; j < 4; ++j) {
                    const int b = wr*64 + mi*16 + fg*4 + j;
                    Vws[(((size_t)s * B_ + b) * 3 + tm) * A_ + n] = (bf16_t)(acc[mi][ni][j] + bias);
                }
        }
    }
}

// ---- attention combine: one wave per (s,b) ----
__global__ __launch_bounds__(256)
void mm_attn_kernel(const bf16_t* __restrict__ Vws,
                    const float* __restrict__ Qws,
                    float* __restrict__ out)
{
    const int wave = threadIdx.x >> 6;
    const int lane = threadIdx.x & 63;
    const int p = blockIdx.x * 4 + wave;
    const int s = p >> 7;
    const int b = p & 127;
    const float*  qrow  = Qws + (size_t)b * A_;
    const bf16_t* vbase = Vws + ((size_t)s * B_ + b) * 3 * A_;

    float4 qv[3];
    bf16x4 vv[3][3];
    float p0 = 0.f, p1 = 0.f, p2 = 0.f;
    #pragma unroll
    for (int j = 0; j < 3; ++j) {
        const int a = lane * 4 + j * 256;
        qv[j]    = *reinterpret_cast<const float4*>(qrow + a);
        vv[0][j] = *reinterpret_cast<const bf16x4*>(vbase + 0*A_ + a);
        vv[1][j] = *reinterpret_cast<const bf16x4*>(vbase + 1*A_ + a);
        vv[2][j] = *reinterpret_cast<const bf16x4*>(vbase + 2*A_ + a);
        p0 += qv[j].x*(float)vv[0][j][0] + qv[j].y*(float)vv[0][j][1]
            + qv[j].z*(float)vv[0][j][2] + qv[j].w*(float)vv[0][j][3];
        p1 += qv[j].x*(float)vv[1][j][0] + qv[j].y*(float)vv[1][j][1]
            + qv[j].z*(float)vv[1][j][2] + qv[j].w*(float)vv[1][j][3];
        p2 += qv[j].x*(float)vv[2][j][0] + qv[j].y*(float)vv[2][j][1]
            + qv[j].z*(float)vv[2][j][2] + qv[j].w*(float)vv[2][j][3];
    }
    #pragma unroll
    for (int d = 1; d < 64; d <<= 1) {
        p0 += __shfl_xor(p0, d);
        p1 += __shfl_xor(p1, d);
        p2 += __shfl_xor(p2, d);
    }
    const float norm = 0.03608439182435161f;   // 1/sqrt(768)
    const float s0 = p0 * norm, s1 = p1 * norm, s2 = p2 * norm;
    const float mx = fmaxf(s0, fmaxf(s1, s2));
    const float e0 = expf(s0 - mx), e1 = expf(s1 - mx), e2 = expf(s2 - mx);
    const float inv = 1.f / (e0 + e1 + e2);
    const float a0 = e0 * inv, a1 = e1 * inv, a2 = e2 * inv;

    float* orow = out + ((size_t)s * B_ + b) * A_;
    #pragma unroll
    for (int j = 0; j < 3; ++j) {
        const int a = lane * 4 + j * 256;
        float4 o;
        o.x = a0*(float)vv[0][j][0] + a1*(float)vv[1][j][0] + a2*(float)vv[2][j][0];
        o.y = a0*(float)vv[0][j][1] + a1*(float)vv[1][j][1] + a2*(float)vv[2][j][1];
        o.z = a0*(float)vv[0][j][2] + a1*(float)vv[1][j][2] + a2*(float)vv[2][j][2];
        o.w = a0*(float)vv[0][j][3] + a1*(float)vv[1][j][3] + a2*(float)vv[2][j][3];
        *reinterpret_cast<float4*>(orow + a) = o;
    }
}

// ============================================================================
// FALLBACK PATH (round-1 GEMM, used only if ws_size is too small)
// ============================================================================
#define LDSPAD 40
__global__ __launch_bounds__(256, 2)
void mm_gemm_kernel(const float* __restrict__ topic,
                    const float* __restrict__ image,
                    const float* __restrict__ text,
                    const float* __restrict__ Wq,
                    const float* __restrict__ bq,
                    const float* __restrict__ Wv,
                    const float* __restrict__ bv,
                    bf16_t* __restrict__ Vws,
                    float*  __restrict__ Qws)
{
    __shared__ bf16_t Alds[128][LDSPAD];
    __shared__ bf16_t Blds[128][LDSPAD];

    const int bid = blockIdx.x;
    const int tid = threadIdx.x;
    const bool isQ = (bid >= S_ * 18);
    int s, tm, tn;
    if (isQ) { s = 0; tm = 0; tn = bid - S_ * 18; }
    else     { s = bid / 18; const int t = bid % 18; tm = t / 6; tn = t % 6; }

    const int ar  = tid >> 1;
    const int aks = (tid & 1) * 16;
    const float* arow;
    if (isQ) {
        arow = topic + (size_t)ar * H_;
    } else {
        const int am  = tm * 128 + ar;
        const int sel = am >> 7;
        const int b   = am & 127;
        if (sel == 0)      arow = topic + (size_t)b * H_;
        else if (sel == 1) arow = image + ((size_t)s * B_ + b) * H_;
        else               arow = text  + ((size_t)s * B_ + b) * H_;
    }
    const int arot = (ar >> 3) & 3;

    const int bn  = tid & 127;
    const int bks = (tid >> 7) * 16;
    const float* wbase = isQ ? Wq : (Wv + (size_t)s * H_ * A_);
    const float* bcolp = wbase + (size_t)(tn * 128 + bn);
    const int brot = (bn >> 3) & 3;

    const int wave = tid >> 6;
    const int lane = tid & 63;
    const int wr = wave >> 1;
    const int wc = wave & 1;
    const int fr = lane & 15;
    const int fg = lane >> 4;

    f32x4 acc[4][4];
    #pragma unroll
    for (int i = 0; i < 4; ++i)
        #pragma unroll
        for (int j = 0; j < 4; ++j)
            acc[i][j] = (f32x4){0.f, 0.f, 0.f, 0.f};

    for (int k0 = 0; k0 < H_; k0 += 32) {
        float4 av[4];
        const float4* ap = reinterpret_cast<const float4*>(arow + k0 + aks);
        #pragma unroll
        for (int i = 0; i < 4; ++i) av[i] = ap[i];
        float bvr[16];
        #pragma unroll
        for (int j = 0; j < 16; ++j) bvr[j] = bcolp[(size_t)(k0 + bks + j) * A_];

        __syncthreads();

        #pragma unroll
        for (int i = 0; i < 4; ++i) {
            const int j = (i + arot) & 3;
            bf16x4 c;
            c[0] = (bf16_t)av[j].x; c[1] = (bf16_t)av[j].y;
            c[2] = (bf16_t)av[j].z; c[3] = (bf16_t)av[j].w;
            *reinterpret_cast<bf16x4*>(&Alds[ar][aks + 4*j]) = c;
        }
        #pragma unroll
        for (int i = 0; i < 4; ++i) {
            const int j = (i + brot) & 3;
            bf16x4 c;
            c[0] = (bf16_t)bvr[4*j+0]; c[1] = (bf16_t)bvr[4*j+1];
            c[2] = (bf16_t)bvr[4*j+2]; c[3] = (bf16_t)bvr[4*j+3];
            *reinterpret_cast<bf16x4*>(&Blds[bn][bks + 4*j]) = c;
        }
        __syncthreads();

        bf16x8 afrag[4], bfrag[4];
        #pragma unroll
        for (int mi = 0; mi < 4; ++mi)
            afrag[mi] = *reinterpret_cast<const bf16x8*>(&Alds[wr*64 + mi*16 + fr][fg*8]);
        #pragma unroll
        for (int ni = 0; ni < 4; ++ni)
            bfrag[ni] = *reinterpret_cast<const bf16x8*>(&Blds[wc*64 + ni*16 + fr][fg*8]);
        #pragma unroll
        for (int mi = 0; mi < 4; ++mi)
            #pragma unroll
            for (int ni = 0; ni < 4; ++ni)
                acc[mi][ni] = __builtin_amdgcn_mfma_f32_16x16x32_bf16(
                    afrag[mi], bfrag[ni], acc[mi][ni], 0, 0, 0);
    }

    if (isQ) {
        #pragma unroll
        for (int ni = 0; ni < 4; ++ni) {
            const int n = tn*128 + wc*64 + ni*16 + fr;
            const float bias = bq[n];
            #pragma unroll
            for (int mi = 0; mi < 4; ++mi)
                #pragma unroll
                for (int j = 0; j < 4; ++j) {
                    const int m = wr*64 + mi*16 + fg*4 + j;
                    Qws[(size_t)m * A_ + n] = acc[mi][ni][j] + bias;
                }
        }
    } else {
        const float* bvrow = bv + (size_t)s * A_;
        #pragma unroll
        for (int ni = 0; ni < 4; ++ni) {
            const int n = tn*128 + wc*64 + ni*16 + fr;
            const float bias = bvrow[n];
            #pragma unroll
            for (int mi = 0; mi < 4; ++mi)
                #pragma unroll
                for (int j = 0; j < 4; ++j) {
                    const int b = wr*64 + mi*16 + fg*4 + j;
                    Vws[(((size_t)s * B_ + b) * 3 + tm) * A_ + n] = (bf16_t)(acc[mi][ni][j] + bias);
                }
        }
    }
}

// ============================================================================
extern "C" void kernel_launch(void* const* d_in, const int* in_sizes, int n_in,
                              void* d_out, int out_size, void* d_ws, size_t ws_size,
                              hipStream_t stream)
{
    const float* topic = (const float*)d_in[0];
    const float* image = (const float*)d_in[1];
    const float* text  = (const float*)d_in[2];
    const float* Wq    = (const float*)d_in[3];
    const float* bq    = (const float*)d_in[4];
    const float* Wv    = (const float*)d_in[5];
    const float* bv    = (const float*)d_in[6];
    float* out = (float*)d_out;

    const size_t szWT = (size_t)(S_ + 1) * A_ * H_ * sizeof(bf16_t);   // 76,677,120
    const size_t szV  = (size_t)S_ * B_ * 3 * A_ * sizeof(bf16_t);     // 37,748,736
    const size_t szQ  = (size_t)B_ * A_ * sizeof(float);               //    393,216
    const size_t szTp = (size_t)B_ * H_ * sizeof(bf16_t);              //    196,608
    const size_t szIm = (size_t)S_ * B_ * H_ * sizeof(bf16_t);         // 12,582,912
    const size_t need = szWT + szV + szQ + szTp + 2 * szIm;            // ~134 MB

    if (ws_size >= need) {
        char* w = (char*)d_ws;
        bf16_t* WT     = (bf16_t*)w;  w += szWT;
        bf16_t* Vws    = (bf16_t*)w;  w += szV;
        float*  Qws    = (float*) w;  w += szQ;
        bf16_t* topicB = (bf16_t*)w;  w += szTp;
        bf16_t* imageB = (bf16_t*)w;  w += szIm;
        bf16_t* textB  = (bf16_t*)w;

        convert_kernel<<<(B_*H_/8 + 255)/256, 256, 0, stream>>>(topic, topicB, B_*H_/8);
        convert_kernel<<<(S_*B_*H_/8)/256,   256, 0, stream>>>(image, imageB, S_*B_*H_/8);
        convert_kernel<<<(S_*B_*H_/8)/256,   256, 0, stream>>>(text,  textB,  S_*B_*H_/8);
        transpose_kernel<<<(S_+1)*576, 256, 0, stream>>>(Wv, Wq, WT);
        gemm_kernel<<<S_*18 + 6, 256, 0, stream>>>(topicB, imageB, textB, WT, bq, bv, Vws, Qws);
        mm_attn_kernel<<<S_*B_/4, 256, 0, stream>>>(Vws, Qws, out);
    } else {
        bf16_t* Vws = (bf16_t*)d_ws;
        float*  Qws = (float*)((char*)d_ws + szV);
        mm_gemm_kernel<<<S_*18 + 6, 256, 0, stream>>>(topic, image, text, Wq, bq, Wv, bv, Vws, Qws);
        mm_attn_kernel<<<S_*B_/4, 256, 0, stream>>>(Vws, Qws, out);
    }
}

// Round 3
// 142.268 us; speedup vs baseline: 1.6565x; 1.0386x over previous
//
#include <hip/hip_runtime.h>
#include <hip/hip_bf16.h>
#include <math.h>

#define S_ 64
#define B_ 128
#define H_ 768
#define A_ 768

typedef __bf16 bf16_t;
typedef __attribute__((ext_vector_type(8))) __bf16 bf16x8;
typedef __attribute__((ext_vector_type(4))) __bf16 bf16x4;
typedef __attribute__((ext_vector_type(4))) float f32x4;

__device__ __forceinline__ bf16x8 pack8(float4 a, float4 b) {
    bf16x8 o;
    o[0]=(bf16_t)a.x; o[1]=(bf16_t)a.y; o[2]=(bf16_t)a.z; o[3]=(bf16_t)a.w;
    o[4]=(bf16_t)b.x; o[5]=(bf16_t)b.y; o[6]=(bf16_t)b.z; o[7]=(bf16_t)b.w;
    return o;
}

// ============================================================================
// FAST PATH
// ============================================================================

// ---- prep: Wv [s][h][a] f32 -> WT [s][a][h] bf16 (s==64 slab = Wq) ----
// 64x64 tiles via LDS (pad 65: 2-way max alias). 128B write segments.
__global__ __launch_bounds__(256)
void transpose_kernel(const float* __restrict__ Wv, const float* __restrict__ Wq,
                      bf16_t* __restrict__ WT) {
    __shared__ float Tl[64][65];
    const int bid = blockIdx.x;
    const int s  = bid / 144;
    const int t  = bid % 144;
    const int th = t / 12, ta = t % 12;
    const float* src = (s < S_) ? (Wv + (size_t)s * H_ * A_) : Wq;
    const int tid = threadIdx.x;

    const int r = tid >> 4, c = (tid & 15) * 4;
    #pragma unroll
    for (int i = 0; i < 4; ++i) {
        const int row = i * 16 + r;
        float4 v = *reinterpret_cast<const float4*>(src + (size_t)(th*64 + row) * A_ + ta*64 + c);
        Tl[row][c+0] = v.x; Tl[row][c+1] = v.y; Tl[row][c+2] = v.z; Tl[row][c+3] = v.w;
    }
    __syncthreads();
    bf16_t* dstbase = WT + (size_t)s * A_ * H_ + (size_t)th * 64;
    #pragma unroll
    for (int i = 0; i < 2; ++i) {
        const int ch = tid + i * 256;
        const int a = ch >> 3, hc = ch & 7;
        bf16x8 o;
        #pragma unroll
        for (int j = 0; j < 8; ++j) o[j] = (bf16_t)Tl[hc*8 + j][a];
        *reinterpret_cast<bf16x8*>(dstbase + (size_t)(ta*64 + a) * H_ + hc*8) = o;
    }
}

// ---- async global->LDS (16 B/lane; LDS dest wave-uniform base + lane*16) ----
__device__ __forceinline__ void glds16(const bf16_t* g, bf16_t* l) {
    __builtin_amdgcn_global_load_lds(
        (const __attribute__((address_space(1))) uint32_t*)(g),
        (__attribute__((address_space(3))) uint32_t*)(l), 16, 0, 0);
}

// ---- main GEMM: 128x128 tile, BK=64, 4 waves, A reg-staged f32->bf16,
//      B via global_load_lds from WT. T2 XOR swizzle (chunk ^= row&7).
//      Grid 1158 = 64*18 + 6Q, XCD-chunked bijective swizzle (T1/m204). ----
__global__ __launch_bounds__(256, 2)
void gemm_kernel(const float* __restrict__ topic,
                 const float* __restrict__ image,
                 const float* __restrict__ text,
                 const bf16_t* __restrict__ WT,
                 const float* __restrict__ bq,
                 const float* __restrict__ bv,
                 bf16_t* __restrict__ Vws, float* __restrict__ Qws)
{
    __shared__ bf16_t Al[128 * 64];   // [row][k], row stride 64 bf16 = 128 B, chunk-swizzled
    __shared__ bf16_t Bl[128 * 64];

    // XCD-chunked bijective remap for grid 1158 (q=144, r=6)
    const int b0 = blockIdx.x;
    const int xcd = b0 & 7, ii = b0 >> 3;
    const int bid = (xcd < 6) ? (xcd * 145 + ii) : (870 + (xcd - 6) * 144 + ii);

    const int tid = threadIdx.x;
    const bool isQ = (bid >= S_ * 18);
    int s, tm, tn;
    if (isQ) { s = S_; tm = 0; tn = bid - S_ * 18; }
    else     { s = bid / 18; const int t = bid % 18; tm = t / 6; tn = t % 6; }

    // ---- A staging setup (f32 source, reg-staged, swizzled ds_write) ----
    const int arow = tid >> 1;              // 0..127
    const int ks   = (tid & 1) * 32;        // k base 0 or 32
    const float* Ap;
    if (isQ || tm == 0) Ap = topic + (size_t)arow * H_;
    else if (tm == 1)   Ap = image + ((size_t)s * B_ + arow) * H_;
    else                Ap = text  + ((size_t)s * B_ + arow) * H_;

    // ---- B staging setup (glds, pre-swizzled global source) ----
    const bf16_t* Bbase = WT + (size_t)s * A_ * H_ + (size_t)(tn * 128) * H_;
    const int wv = tid >> 6, lane = tid & 63;
    const bf16_t* gB[4];
    bf16_t* lB[4];
    #pragma unroll
    for (int i = 0; i < 4; ++i) {
        const int p = wv * 256 + i * 64 + lane;      // 16B slot 0..1023
        const int r = p >> 3, cch = p & 7;
        gB[i] = Bbase + (size_t)r * H_ + (size_t)(cch ^ (r & 7)) * 8;
        lB[i] = Bl + (size_t)(wv * 256 + i * 64) * 8;   // wave-uniform
    }

    const int wr = wv >> 1, wc = wv & 1;
    const int fr = lane & 15, fg = lane >> 4;
    const int fx = fr & 7;                   // swizzle key for frag reads

    f32x4 acc[4][4];
    #pragma unroll
    for (int i = 0; i < 4; ++i)
        #pragma unroll
        for (int j = 0; j < 4; ++j)
            acc[i][j] = (f32x4){0.f, 0.f, 0.f, 0.f};

    for (int k0 = 0; k0 < H_; k0 += 64) {
        // A global loads (f32), issued early
        float4 f[8];
        const float4* ap = reinterpret_cast<const float4*>(Ap + k0 + ks);
        #pragma unroll
        for (int i = 0; i < 8; ++i) f[i] = ap[i];

        __syncthreads();                         // prev iter frag reads done
        #pragma unroll
        for (int i = 0; i < 4; ++i) glds16(gB[i] + k0, lB[i]);   // B async
        #pragma unroll
        for (int j = 0; j < 4; ++j) {            // A cvt + swizzled write
            const int cw = (tid & 1) * 4 + j;
            const int cs = cw ^ (arow & 7);
            *reinterpret_cast<bf16x8*>(Al + arow * 64 + cs * 8) = pack8(f[2*j], f[2*j+1]);
        }
        __syncthreads();                         // drains vmcnt + lgkm

        bf16x8 af[2][4], bf_[2][4];
        #pragma unroll
        for (int kk = 0; kk < 2; ++kk) {
            #pragma unroll
            for (int mi = 0; mi < 4; ++mi)
                af[kk][mi] = *reinterpret_cast<const bf16x8*>(
                    Al + (wr*64 + mi*16 + fr) * 64 + (((kk<<2)|fg) ^ fx) * 8);
            #pragma unroll
            for (int ni = 0; ni < 4; ++ni)
                bf_[kk][ni] = *reinterpret_cast<const bf16x8*>(
                    Bl + (wc*64 + ni*16 + fr) * 64 + (((kk<<2)|fg) ^ fx) * 8);
        }
        #pragma unroll
        for (int kk = 0; kk < 2; ++kk)
            #pragma unroll
            for (int mi = 0; mi < 4; ++mi)
                #pragma unroll
                for (int ni = 0; ni < 4; ++ni)
                    acc[mi][ni] = __builtin_amdgcn_mfma_f32_16x16x32_bf16(
                        af[kk][mi], bf_[kk][ni], acc[mi][ni], 0, 0, 0);
    }

    // epilogue: C/D map col = lane&15, row = (lane>>4)*4 + j
    if (isQ) {
        #pragma unroll
        for (int ni = 0; ni < 4; ++ni) {
            const int n = tn*128 + wc*64 + ni*16 + fr;
            const float bias = bq[n];
            #pragma unroll
            for (int mi = 0; mi < 4; ++mi)
                #pragma unroll
                for (int j = 0; j < 4; ++j) {
                    const int m = wr*64 + mi*16 + fg*4 + j;
                    Qws[(size_t)m * A_ + n] = acc[mi][ni][j] + bias;
                }
        }
    } else {
        const float* bvrow = bv + (size_t)s * A_;
        #pragma unroll
        for (int ni = 0; ni < 4; ++ni) {
            const int n = tn*128 + wc*64 + ni*16 + fr;
            const float bias = bvrow[n];
            #pragma unroll
            for (int mi = 0; mi < 4; ++mi)
                #pragma unroll
                for (int j = 0; j < 4; ++j) {
                    const int b = wr*64 + mi*16 + fg*4 + j;
                    Vws[(((size_t)s * B_ + b) * 3 + tm) * A_ + n] = (bf16_t)(acc[mi][ni][j] + bias);
                }
        }
    }
}

// ---- attention combine: one wave per (s,b) ----
__global__ __launch_bounds__(256)
void mm_attn_kernel(const bf16_t* __restrict__ Vws,
                    const float* __restrict__ Qws,
                    float* __restrict__ out)
{
    const int wave = threadIdx.x >> 6;
    const int lane = threadIdx.x & 63;
    const int p = blockIdx.x * 4 + wave;
    const int s = p >> 7;
    const int b = p & 127;
    const float*  qrow  = Qws + (size_t)b * A_;
    const bf16_t* vbase = Vws + ((size_t)s * B_ + b) * 3 * A_;

    float4 qv[3];
    bf16x4 vv[3][3];
    float p0 = 0.f, p1 = 0.f, p2 = 0.f;
    #pragma unroll
    for (int j = 0; j < 3; ++j) {
        const int a = lane * 4 + j * 256;
        qv[j]    = *reinterpret_cast<const float4*>(qrow + a);
        vv[0][j] = *reinterpret_cast<const bf16x4*>(vbase + 0*A_ + a);
        vv[1][j] = *reinterpret_cast<const bf16x4*>(vbase + 1*A_ + a);
        vv[2][j] = *reinterpret_cast<const bf16x4*>(vbase + 2*A_ + a);
        p0 += qv[j].x*(float)vv[0][j][0] + qv[j].y*(float)vv[0][j][1]
            + qv[j].z*(float)vv[0][j][2] + qv[j].w*(float)vv[0][j][3];
        p1 += qv[j].x*(float)vv[1][j][0] + qv[j].y*(float)vv[1][j][1]
            + qv[j].z*(float)vv[1][j][2] + qv[j].w*(float)vv[1][j][3];
        p2 += qv[j].x*(float)vv[2][j][0] + qv[j].y*(float)vv[2][j][1]
            + qv[j].z*(float)vv[2][j][2] + qv[j].w*(float)vv[2][j][3];
    }
    #pragma unroll
    for (int d = 1; d < 64; d <<= 1) {
        p0 += __shfl_xor(p0, d);
        p1 += __shfl_xor(p1, d);
        p2 += __shfl_xor(p2, d);
    }
    const float norm = 0.03608439182435161f;   // 1/sqrt(768)
    const float s0 = p0 * norm, s1 = p1 * norm, s2 = p2 * norm;
    const float mx = fmaxf(s0, fmaxf(s1, s2));
    const float e0 = expf(s0 - mx), e1 = expf(s1 - mx), e2 = expf(s2 - mx);
    const float inv = 1.f / (e0 + e1 + e2);
    const float a0 = e0 * inv, a1 = e1 * inv, a2 = e2 * inv;

    float* orow = out + ((size_t)s * B_ + b) * A_;
    #pragma unroll
    for (int j = 0; j < 3; ++j) {
        const int a = lane * 4 + j * 256;
        float4 o;
        o.x = a0*(float)vv[0][j][0] + a1*(float)vv[1][j][0] + a2*(float)vv[2][j][0];
        o.y = a0*(float)vv[0][j][1] + a1*(float)vv[1][j][1] + a2*(float)vv[2][j][1];
        o.z = a0*(float)vv[0][j][2] + a1*(float)vv[1][j][2] + a2*(float)vv[2][j][2];
        o.w = a0*(float)vv[0][j][3] + a1*(float)vv[1][j][3] + a2*(float)vv[2][j][3];
        *reinterpret_cast<float4*>(orow + a) = o;
    }
}

// ============================================================================
// FALLBACK PATH (round-1 GEMM, used only if ws_size is too small)
// ============================================================================
#define LDSPAD 40
__global__ __launch_bounds__(256, 2)
void mm_gemm_kernel(const float* __restrict__ topic,
                    const float* __restrict__ image,
                    const float* __restrict__ text,
                    const float* __restrict__ Wq,
                    const float* __restrict__ bq,
                    const float* __restrict__ Wv,
                    const float* __restrict__ bv,
                    bf16_t* __restrict__ Vws,
                    float*  __restrict__ Qws)
{
    __shared__ bf16_t Alds[128][LDSPAD];
    __shared__ bf16_t Blds[128][LDSPAD];

    const int bid = blockIdx.x;
    const int tid = threadIdx.x;
    const bool isQ = (bid >= S_ * 18);
    int s, tm, tn;
    if (isQ) { s = 0; tm = 0; tn = bid - S_ * 18; }
    else     { s = bid / 18; const int t = bid % 18; tm = t / 6; tn = t % 6; }

    const int ar  = tid >> 1;
    const int aks = (tid & 1) * 16;
    const float* arow;
    if (isQ) {
        arow = topic + (size_t)ar * H_;
    } else {
        const int am  = tm * 128 + ar;
        const int sel = am >> 7;
        const int b   = am & 127;
        if (sel == 0)      arow = topic + (size_t)b * H_;
        else if (sel == 1) arow = image + ((size_t)s * B_ + b) * H_;
        else               arow = text  + ((size_t)s * B_ + b) * H_;
    }
    const int arot = (ar >> 3) & 3;

    const int bn  = tid & 127;
    const int bks = (tid >> 7) * 16;
    const float* wbase = isQ ? Wq : (Wv + (size_t)s * H_ * A_);
    const float* bcolp = wbase + (size_t)(tn * 128 + bn);
    const int brot = (bn >> 3) & 3;

    const int wave = tid >> 6;
    const int lane = tid & 63;
    const int wr = wave >> 1;
    const int wc = wave & 1;
    const int fr = lane & 15;
    const int fg = lane >> 4;

    f32x4 acc[4][4];
    #pragma unroll
    for (int i = 0; i < 4; ++i)
        #pragma unroll
        for (int j = 0; j < 4; ++j)
            acc[i][j] = (f32x4){0.f, 0.f, 0.f, 0.f};

    for (int k0 = 0; k0 < H_; k0 += 32) {
        float4 av[4];
        const float4* ap = reinterpret_cast<const float4*>(arow + k0 + aks);
        #pragma unroll
        for (int i = 0; i < 4; ++i) av[i] = ap[i];
        float bvr[16];
        #pragma unroll
        for (int j = 0; j < 16; ++j) bvr[j] = bcolp[(size_t)(k0 + bks + j) * A_];

        __syncthreads();

        #pragma unroll
        for (int i = 0; i < 4; ++i) {
            const int j = (i + arot) & 3;
            bf16x4 c;
            c[0] = (bf16_t)av[j].x; c[1] = (bf16_t)av[j].y;
            c[2] = (bf16_t)av[j].z; c[3] = (bf16_t)av[j].w;
            *reinterpret_cast<bf16x4*>(&Alds[ar][aks + 4*j]) = c;
        }
        #pragma unroll
        for (int i = 0; i < 4; ++i) {
            const int j = (i + brot) & 3;
            bf16x4 c;
            c[0] = (bf16_t)bvr[4*j+0]; c[1] = (bf16_t)bvr[4*j+1];
            c[2] = (bf16_t)bvr[4*j+2]; c[3] = (bf16_t)bvr[4*j+3];
            *reinterpret_cast<bf16x4*>(&Blds[bn][bks + 4*j]) = c;
        }
        __syncthreads();

        bf16x8 afrag[4], bfrag[4];
        #pragma unroll
        for (int mi = 0; mi < 4; ++mi)
            afrag[mi] = *reinterpret_cast<const bf16x8*>(&Alds[wr*64 + mi*16 + fr][fg*8]);
        #pragma unroll
        for (int ni = 0; ni < 4; ++ni)
            bfrag[ni] = *reinterpret_cast<const bf16x8*>(&Blds[wc*64 + ni*16 + fr][fg*8]);
        #pragma unroll
        for (int mi = 0; mi < 4; ++mi)
            #pragma unroll
            for (int ni = 0; ni < 4; ++ni)
                acc[mi][ni] = __builtin_amdgcn_mfma_f32_16x16x32_bf16(
                    afrag[mi], bfrag[ni], acc[mi][ni], 0, 0, 0);
    }

    if (isQ) {
        #pragma unroll
        for (int ni = 0; ni < 4; ++ni) {
            const int n = tn*128 + wc*64 + ni*16 + fr;
            const float bias = bq[n];
            #pragma unroll
            for (int mi = 0; mi < 4; ++mi)
                #pragma unroll
                for (int j = 0; j < 4; ++j) {
                    const int m = wr*64 + mi*16 + fg*4 + j;
                    Qws[(size_t)m * A_ + n] = acc[mi][ni][j] + bias;
                }
        }
    } else {
        const float* bvrow = bv + (size_t)s * A_;
        #pragma unroll
        for (int ni = 0; ni < 4; ++ni) {
            const int n = tn*128 + wc*64 + ni*16 + fr;
            const float bias = bvrow[n];
            #pragma unroll
            for (int mi = 0; mi < 4; ++mi)
                #pragma unroll
                for (int j = 0; j < 4; ++j) {
                    const int b = wr*64 + mi*16 + fg*4 + j;
                    Vws[(((size_t)s * B_ + b) * 3 + tm) * A_ + n] = (bf16_t)(acc[mi][ni][j] + bias);
                }
        }
    }
}

// ============================================================================
extern "C" void kernel_launch(void* const* d_in, const int* in_sizes, int n_in,
                              void* d_out, int out_size, void* d_ws, size_t ws_size,
                              hipStream_t stream)
{
    const float* topic = (const float*)d_in[0];
    const float* image = (const float*)d_in[1];
    const float* text  = (const float*)d_in[2];
    const float* Wq    = (const float*)d_in[3];
    const float* bq    = (const float*)d_in[4];
    const float* Wv    = (const float*)d_in[5];
    const float* bv    = (const float*)d_in[6];
    float* out = (float*)d_out;

    const size_t szWT = (size_t)(S_ + 1) * A_ * H_ * sizeof(bf16_t);   // 76,677,120
    const size_t szV  = (size_t)S_ * B_ * 3 * A_ * sizeof(bf16_t);     // 37,748,736
    const size_t szQ  = (size_t)B_ * A_ * sizeof(float);               //    393,216
    const size_t need = szWT + szV + szQ;                              // ~115 MB

    if (ws_size >= need) {
        char* w = (char*)d_ws;
        bf16_t* WT  = (bf16_t*)w;  w += szWT;
        bf16_t* Vws = (bf16_t*)w;  w += szV;
        float*  Qws = (float*) w;

        transpose_kernel<<<(S_+1)*144, 256, 0, stream>>>(Wv, Wq, WT);
        gemm_kernel<<<S_*18 + 6, 256, 0, stream>>>(topic, image, text, WT, bq, bv, Vws, Qws);
        mm_attn_kernel<<<S_*B_/4, 256, 0, stream>>>(Vws, Qws, out);
    } else {
        bf16_t* Vws = (bf16_t*)d_ws;
        float*  Qws = (float*)((char*)d_ws + szV);
        mm_gemm_kernel<<<S_*18 + 6, 256, 0, stream>>>(topic, image, text, Wq, bq, Wv, bv, Vws, Qws);
        mm_attn_kernel<<<S_*B_/4, 256, 0, stream>>>(Vws, Qws, out);
    }
}